// Round 1
// baseline (1037.417 us; speedup 1.0000x reference)
//
#include <hip/hip_runtime.h>
#include <hip/hip_bf16.h>
#include <math.h>

// ---------------------------------------------------------------------------
// Swin Transformer 3D block, MI355X (gfx950)
// B=1, D=16, H=56, W=56, C=128, NH=4, HEAD=32, window 8x7x7 (N=392), shift 4,3,3
// Round 0: correctness-first. bf16 MFMA for the 4 GEMMs, fp32 VALU attention.
// ---------------------------------------------------------------------------

typedef short s16x8 __attribute__((ext_vector_type(8)));
typedef float fp32x4 __attribute__((ext_vector_type(4)));

#define T_TOT 50176      // total tokens = 128 windows * 392
#define N_TOK 392
#define N_WIN 128

__device__ __forceinline__ unsigned short f2bf(float f) {
    union { float f; unsigned u; } v; v.f = f;
    unsigned r = v.u + 0x7FFFu + ((v.u >> 16) & 1u);   // RNE
    return (unsigned short)(r >> 16);
}
__device__ __forceinline__ float bf2f(unsigned short u) {
    union { unsigned u; float f; } v; v.u = ((unsigned)u) << 16;
    return v.f;
}

// ---------------------------------------------------------------------------
// Weight fp32 -> bf16 conversion (one small kernel, all four weights)
// ---------------------------------------------------------------------------
__global__ void cvt_w_k(const float* __restrict__ wq, const float* __restrict__ wp,
                        const float* __restrict__ w1, const float* __restrict__ w2,
                        unsigned short* __restrict__ oq, unsigned short* __restrict__ op,
                        unsigned short* __restrict__ o1, unsigned short* __restrict__ o2)
{
    int i = blockIdx.x * 256 + threadIdx.x;
    if (i < 384 * 128) oq[i] = f2bf(wq[i]);
    if (i < 128 * 128) op[i] = f2bf(wp[i]);
    if (i < 512 * 128) { o1[i] = f2bf(w1[i]); o2[i] = f2bf(w2[i]); }
}

// ---------------------------------------------------------------------------
// Relative-position bias table: bias[h][i][j] = rel_pos_table[rel_idx(i,j)][h]
// ---------------------------------------------------------------------------
__global__ void bias_tab_k(const float* __restrict__ tab, float* __restrict__ out)
{
    int idx = blockIdx.x * 256 + threadIdx.x;
    if (idx >= 4 * N_TOK * N_TOK) return;
    int h = idx / (N_TOK * N_TOK), r = idx % (N_TOK * N_TOK);
    int i = r / N_TOK, j = r % N_TOK;
    int di = i / 49, hi = (i % 49) / 7, wi = i % 7;
    int dj = j / 49, hj = (j % 49) / 7, wj = j % 7;
    int rel = (di - dj + 7) * 169 + (hi - hj + 6) * 13 + (wi - wj + 6);
    out[idx] = tab[rel * 4 + h];
}

// ---------------------------------------------------------------------------
// LN1 + cyclic shift (roll -4,-3,-3) + window partition -> bf16 (T_TOT,128)
// one wave per token
// ---------------------------------------------------------------------------
__global__ __launch_bounds__(256) void ln1_part_k(
    const float* __restrict__ x, const float* __restrict__ w,
    const float* __restrict__ b, unsigned short* __restrict__ xw)
{
    const int t = blockIdx.x * 4 + (threadIdx.x >> 6);
    const int lane = threadIdx.x & 63;
    const int win = t / N_TOK, n = t % N_TOK;
    const int wd = win >> 6, wh = (win >> 3) & 7, ww = win & 7;
    const int td = n / 49, rr = n % 49, th = rr / 7, tw = rr % 7;
    const int gd = wd * 8 + td, gh = wh * 7 + th, gw = ww * 7 + tw;
    const int sd = (gd + 4) & 15;
    int sh = gh + 3; if (sh >= 56) sh -= 56;
    int sw = gw + 3; if (sw >= 56) sw -= 56;
    const float* px = x + (((size_t)sd * 56 + sh) * 56 + sw) * 128;
    float v0 = px[lane], v1 = px[lane + 64];
    float s = v0 + v1, s2 = v0 * v0 + v1 * v1;
#pragma unroll
    for (int o = 32; o > 0; o >>= 1) { s += __shfl_xor(s, o); s2 += __shfl_xor(s2, o); }
    float mu = s * (1.f / 128.f);
    float var = s2 * (1.f / 128.f) - mu * mu;
    float rstd = rsqrtf(var + 1e-5f);
    unsigned short* po = xw + (size_t)t * 128;
    po[lane]      = f2bf((v0 - mu) * rstd * w[lane]      + b[lane]);
    po[lane + 64] = f2bf((v1 - mu) * rstd * w[lane + 64] + b[lane + 64]);
}

// ---------------------------------------------------------------------------
// LN2 (image token order) -> bf16
// ---------------------------------------------------------------------------
__global__ __launch_bounds__(256) void ln2_k(
    const float* __restrict__ x1, const float* __restrict__ w,
    const float* __restrict__ b, unsigned short* __restrict__ xn)
{
    const int t = blockIdx.x * 4 + (threadIdx.x >> 6);
    const int lane = threadIdx.x & 63;
    const float* px = x1 + (size_t)t * 128;
    float v0 = px[lane], v1 = px[lane + 64];
    float s = v0 + v1, s2 = v0 * v0 + v1 * v1;
#pragma unroll
    for (int o = 32; o > 0; o >>= 1) { s += __shfl_xor(s, o); s2 += __shfl_xor(s2, o); }
    float mu = s * (1.f / 128.f);
    float var = s2 * (1.f / 128.f) - mu * mu;
    float rstd = rsqrtf(var + 1e-5f);
    unsigned short* po = xn + (size_t)t * 128;
    po[lane]      = f2bf((v0 - mu) * rstd * w[lane]      + b[lane]);
    po[lane + 64] = f2bf((v1 - mu) * rstd * w[lane + 64] + b[lane + 64]);
}

// ---------------------------------------------------------------------------
// bf16 MFMA GEMM, 128x128 tile, 4 waves (2x2), 64x64 per wave, BK=64.
// A: (M,K) bf16 row-major.  Bt: (N,K) bf16 row-major (i.e. B transposed).
// EPI: 0 = qkv (bias, scale q cols<128, bf16 out stride 384)
//      1 = proj (bias + window_reverse + roll + residual(x), fp32 out = x1)
//      2 = fc1  (bias + exact gelu, bf16 out stride 512)
//      3 = fc2  (bias + residual(x1), fp32 out stride 128)
// ---------------------------------------------------------------------------
template<int K, int EPI>
__global__ __launch_bounds__(256, 2) void gemm_k(
    const unsigned short* __restrict__ A,
    const unsigned short* __restrict__ Bt,
    const float* __restrict__ bias,
    const float* __restrict__ resid,
    void* __restrict__ outp)
{
    __shared__ __align__(16) unsigned short Asl[128 * 64];
    __shared__ __align__(16) unsigned short Bsl[128 * 64];
    const int bm = blockIdx.x * 128;
    const int bn = blockIdx.y * 128;
    const int tid = threadIdx.x;
    const int lane = tid & 63;
    const int wave = tid >> 6;
    const int wr = wave >> 1, wc = wave & 1;
    const int lr = lane & 15;            // A row / B col within 16-frag
    const int lk = (lane >> 4) << 3;     // k offset within 32-step

    fp32x4 acc[4][4];
#pragma unroll
    for (int i = 0; i < 4; ++i)
#pragma unroll
        for (int j = 0; j < 4; ++j) acc[i][j] = {0.f, 0.f, 0.f, 0.f};

    for (int ks = 0; ks < K; ks += 64) {
        __syncthreads();
#pragma unroll
        for (int it = 0; it < 4; ++it) {
            int chunk = it * 256 + tid;          // 1024 chunks x 8 bf16 = 128x64
            int row = chunk >> 3;
            int kc = (chunk & 7) << 3;
            *(uint4*)&Asl[row * 64 + kc] =
                *(const uint4*)&A[(size_t)(bm + row) * K + ks + kc];
            *(uint4*)&Bsl[row * 64 + kc] =
                *(const uint4*)&Bt[(size_t)(bn + row) * K + ks + kc];
        }
        __syncthreads();
#pragma unroll
        for (int kk = 0; kk < 64; kk += 32) {
            s16x8 af[4], bfr[4];
#pragma unroll
            for (int mb = 0; mb < 4; ++mb)
                af[mb] = *(const s16x8*)&Asl[(wr * 64 + mb * 16 + lr) * 64 + kk + lk];
#pragma unroll
            for (int nb = 0; nb < 4; ++nb)
                bfr[nb] = *(const s16x8*)&Bsl[(wc * 64 + nb * 16 + lr) * 64 + kk + lk];
#pragma unroll
            for (int mb = 0; mb < 4; ++mb)
#pragma unroll
                for (int nb = 0; nb < 4; ++nb)
                    acc[mb][nb] = __builtin_amdgcn_mfma_f32_16x16x32_bf16(
                        af[mb], bfr[nb], acc[mb][nb], 0, 0, 0);
        }
    }

    // C/D layout: col = lane&15, row = (lane>>4)*4 + reg   [m89-verified]
    const int crow = (lane >> 4) << 2;
    const int ccol = lane & 15;
#pragma unroll
    for (int mb = 0; mb < 4; ++mb) {
#pragma unroll
        for (int nb = 0; nb < 4; ++nb) {
#pragma unroll
            for (int r = 0; r < 4; ++r) {
                const int grow = bm + wr * 64 + mb * 16 + crow + r;
                const int gcol = bn + wc * 64 + nb * 16 + ccol;
                float v = acc[mb][nb][r] + bias[gcol];
                if (EPI == 0) {
                    if (gcol < 128) v *= 0.17677669529663687f;   // HEAD^-0.5
                    ((unsigned short*)outp)[(size_t)grow * 384 + gcol] = f2bf(v);
                } else if (EPI == 1) {
                    // window token -> image coords (reverse + roll +4,+3,+3)
                    int w  = grow / N_TOK, n = grow % N_TOK;
                    int wd = w >> 6, wh = (w >> 3) & 7, ww = w & 7;
                    int td = n / 49, rr = n % 49, th = rr / 7, tw = rr % 7;
                    int gd = wd * 8 + td, gh = wh * 7 + th, gw = ww * 7 + tw;
                    int sd = (gd + 4) & 15;
                    int sh = gh + 3; if (sh >= 56) sh -= 56;
                    int sw = gw + 3; if (sw >= 56) sw -= 56;
                    size_t oi = (((size_t)sd * 56 + sh) * 56 + sw) * 128 + gcol;
                    ((float*)outp)[oi] = v + resid[oi];
                } else if (EPI == 2) {
                    v = 0.5f * v * (1.f + erff(v * 0.70710678118654752f));
                    ((unsigned short*)outp)[(size_t)grow * 512 + gcol] = f2bf(v);
                } else {
                    size_t oi = (size_t)grow * 128 + gcol;
                    ((float*)outp)[oi] = v + resid[oi];
                }
            }
        }
    }
}

// ---------------------------------------------------------------------------
// Attention: one block per (window, head). 512 threads = 8 waves.
// K,V staged fp32 transposed in LDS [32][401] (401-pad -> conflict-free PV).
// Wave-parallel scores + softmax (shfl reductions over 64 lanes).
// ---------------------------------------------------------------------------
__global__ __launch_bounds__(512, 1) void attn_k(
    const unsigned short* __restrict__ qkv,
    const float* __restrict__ btab,
    unsigned short* __restrict__ y)
{
    __shared__ float Ksh[32][401];
    __shared__ float Vsh[32][401];
    __shared__ float Psh[8][400];
    const int blk = blockIdx.x;
    const int wI = blk >> 2, h = blk & 3;
    const int tid = threadIdx.x, wave = tid >> 6, lane = tid & 63;
    const unsigned short* base = qkv + (size_t)wI * N_TOK * 384;

    for (int idx = tid; idx < N_TOK * 32; idx += 512) {
        int n = idx >> 5, c = idx & 31;
        Ksh[c][n] = bf2f(base[n * 384 + 128 + h * 32 + c]);
        Vsh[c][n] = bf2f(base[n * 384 + 256 + h * 32 + c]);
    }
    __syncthreads();

    const int wd = wI >> 6, wh = (wI >> 3) & 7, ww = wI & 7;
    const bool boundary = (wd == 1) | (wh == 7) | (ww == 7);

    for (int i = wave; i < N_TOK; i += 8) {
        float qv[32];
        const unsigned short* qp = base + (size_t)i * 384 + h * 32;
#pragma unroll
        for (int c = 0; c < 32; ++c) qv[c] = bf2f(qp[c]);   // broadcast loads

        int ri = 0;
        if (boundary) {
            int td = i / 49, rr2 = i % 49, th = rr2 / 7, tw = rr2 % 7;
            int gd = wd * 8 + td, gh = wh * 7 + th, gw = ww * 7 + tw;
            ri = ((gd < 8) ? 0 : ((gd < 12) ? 9 : 18)) +
                 ((gh < 49) ? 0 : ((gh < 53) ? 3 : 6)) +
                 ((gw < 49) ? 0 : ((gw < 53) ? 1 : 2));
        }
        float sv[7];
        float smax = -1e30f;
        const float* brow = btab + ((size_t)h * N_TOK + i) * N_TOK;
#pragma unroll
        for (int jb = 0; jb < 7; ++jb) {
            int j = jb * 64 + lane;
            int jj = (j < N_TOK) ? j : (N_TOK - 1);
            float s = 0.f;
#pragma unroll
            for (int c = 0; c < 32; ++c) s += qv[c] * Ksh[c][jj];
            s += brow[jj];
            if (boundary) {
                int td = jj / 49, rr2 = jj % 49, th = rr2 / 7, tw = rr2 % 7;
                int gd = wd * 8 + td, gh = wh * 7 + th, gw = ww * 7 + tw;
                int rj = ((gd < 8) ? 0 : ((gd < 12) ? 9 : 18)) +
                         ((gh < 49) ? 0 : ((gh < 53) ? 3 : 6)) +
                         ((gw < 49) ? 0 : ((gw < 53) ? 1 : 2));
                if (rj != ri) s -= 100.f;
            }
            s = (j < N_TOK) ? s : -1e30f;
            sv[jb] = s;
            smax = fmaxf(smax, s);
        }
#pragma unroll
        for (int o = 32; o > 0; o >>= 1) smax = fmaxf(smax, __shfl_xor(smax, o));
        float ssum = 0.f;
#pragma unroll
        for (int jb = 0; jb < 7; ++jb) {
            float p = __expf(sv[jb] - smax);
            p = (jb * 64 + lane < N_TOK) ? p : 0.f;
            sv[jb] = p;
            ssum += p;
        }
#pragma unroll
        for (int o = 32; o > 0; o >>= 1) ssum += __shfl_xor(ssum, o);
        const float rs = 1.f / ssum;
#pragma unroll
        for (int jb = 0; jb < 7; ++jb) {
            int j = jb * 64 + lane;
            if (j < N_TOK) Psh[wave][j] = sv[jb] * rs;
        }
        // PV: lane = (half, c); 196 j per half, shfl-combine halves
        const int c = lane & 31, hf = lane >> 5;
        float o0 = 0.f;
        const float* pr = Psh[wave];
        const float* vr = Vsh[c];
#pragma unroll 4
        for (int j = hf * 196; j < hf * 196 + 196; ++j)
            o0 += pr[j] * vr[j];
        o0 += __shfl_xor(o0, 32);
        if (hf == 0)
            y[((size_t)wI * N_TOK + i) * 128 + h * 32 + c] = f2bf(o0);
    }
}

// ---------------------------------------------------------------------------
extern "C" void kernel_launch(void* const* d_in, const int* in_sizes, int n_in,
                              void* d_out, int out_size, void* d_ws, size_t ws_size,
                              hipStream_t stream)
{
    const float* x      = (const float*)d_in[0];
    const float* n1w    = (const float*)d_in[1];
    const float* n1b    = (const float*)d_in[2];
    const float* qkv_w  = (const float*)d_in[3];
    const float* qkv_b  = (const float*)d_in[4];
    const float* rpt    = (const float*)d_in[5];
    const float* proj_w = (const float*)d_in[6];
    const float* proj_b = (const float*)d_in[7];
    const float* n2w    = (const float*)d_in[8];
    const float* n2b    = (const float*)d_in[9];
    const float* fc1_w  = (const float*)d_in[10];
    const float* fc1_b  = (const float*)d_in[11];
    const float* fc2_w  = (const float*)d_in[12];
    const float* fc2_b  = (const float*)d_in[13];

    char* ws = (char*)d_ws;
    unsigned short* xw  = (unsigned short*)(ws);                  // T*128 bf16
    unsigned short* qkv = (unsigned short*)(ws + 12845056);       // T*384 bf16
    unsigned short* y   = (unsigned short*)(ws + 51380224);       // T*128 bf16
    float*          x1  = (float*)         (ws + 64225280);       // T*128 f32
    unsigned short* xn  = (unsigned short*)(ws + 89915392);       // T*128 bf16
    unsigned short* hid = (unsigned short*)(ws + 102760448);      // T*512 bf16
    unsigned short* wq  = (unsigned short*)(ws + 154140672);      // 384*128 bf16
    unsigned short* wp  = (unsigned short*)(ws + 154238976);      // 128*128 bf16
    unsigned short* w1  = (unsigned short*)(ws + 154271744);      // 512*128 bf16
    unsigned short* w2  = (unsigned short*)(ws + 154402816);      // 128*512 bf16
    float*          bt  = (float*)         (ws + 154533888);      // 4*392*392 f32

    hipLaunchKernelGGL(cvt_w_k, dim3(256), dim3(256), 0, stream,
                       qkv_w, proj_w, fc1_w, fc2_w, wq, wp, w1, w2);
    hipLaunchKernelGGL(bias_tab_k, dim3((4 * N_TOK * N_TOK + 255) / 256), dim3(256),
                       0, stream, rpt, bt);
    hipLaunchKernelGGL(ln1_part_k, dim3(T_TOT / 4), dim3(256), 0, stream,
                       x, n1w, n1b, xw);
    hipLaunchKernelGGL((gemm_k<128, 0>), dim3(392, 3), dim3(256), 0, stream,
                       xw, wq, qkv_b, (const float*)nullptr, (void*)qkv);
    hipLaunchKernelGGL(attn_k, dim3(512), dim3(512), 0, stream, qkv, bt, y);
    hipLaunchKernelGGL((gemm_k<128, 1>), dim3(392, 1), dim3(256), 0, stream,
                       y, wp, proj_b, x, (void*)x1);
    hipLaunchKernelGGL(ln2_k, dim3(T_TOT / 4), dim3(256), 0, stream,
                       x1, n2w, n2b, xn);
    hipLaunchKernelGGL((gemm_k<128, 2>), dim3(392, 4), dim3(256), 0, stream,
                       xn, w1, fc1_b, (const float*)nullptr, (void*)hid);
    hipLaunchKernelGGL((gemm_k<512, 3>), dim3(392, 1), dim3(256), 0, stream,
                       hid, w2, fc2_b, x1, d_out);
}

// Round 4
// 302.937 us; speedup vs baseline: 3.4245x; 3.4245x over previous
//
#include <hip/hip_runtime.h>
#include <hip/hip_bf16.h>
#include <math.h>

// ---------------------------------------------------------------------------
// Swin Transformer 3D block, MI355X (gfx950)
// B=1, D=16, H=56, W=56, C=128, NH=4, HEAD=32, window 8x7x7 (N=392), shift 4,3,3
// Round 3: identical resubmit (rounds 2-3 died at container acquire — no
// timing dict => infra, not kernel). MFMA attention, tokens padded 392->416.
// ---------------------------------------------------------------------------

typedef short s16x8 __attribute__((ext_vector_type(8)));
typedef unsigned short u16x8 __attribute__((ext_vector_type(8)));
typedef float fp32x4 __attribute__((ext_vector_type(4)));

#define T_TOT 50176      // total tokens = 128 windows * 392
#define N_TOK 392
#define N_WIN 128

__device__ __forceinline__ unsigned short f2bf(float f) {
    union { float f; unsigned u; } v; v.f = f;
    unsigned r = v.u + 0x7FFFu + ((v.u >> 16) & 1u);   // RNE
    return (unsigned short)(r >> 16);
}
__device__ __forceinline__ float bf2f(unsigned short u) {
    union { unsigned u; float f; } v; v.u = ((unsigned)u) << 16;
    return v.f;
}

// ---------------------------------------------------------------------------
// Weight fp32 -> bf16 conversion (one small kernel, all four weights)
// ---------------------------------------------------------------------------
__global__ void cvt_w_k(const float* __restrict__ wq, const float* __restrict__ wp,
                        const float* __restrict__ w1, const float* __restrict__ w2,
                        unsigned short* __restrict__ oq, unsigned short* __restrict__ op,
                        unsigned short* __restrict__ o1, unsigned short* __restrict__ o2)
{
    int i = blockIdx.x * 256 + threadIdx.x;
    if (i < 384 * 128) oq[i] = f2bf(wq[i]);
    if (i < 128 * 128) op[i] = f2bf(wp[i]);
    if (i < 512 * 128) { o1[i] = f2bf(w1[i]); o2[i] = f2bf(w2[i]); }
}

// ---------------------------------------------------------------------------
// Relative-position bias table: bias[h][i][j] = rel_pos_table[rel_idx(i,j)][h]
// ---------------------------------------------------------------------------
__global__ void bias_tab_k(const float* __restrict__ tab, float* __restrict__ out)
{
    int idx = blockIdx.x * 256 + threadIdx.x;
    if (idx >= 4 * N_TOK * N_TOK) return;
    int h = idx / (N_TOK * N_TOK), r = idx % (N_TOK * N_TOK);
    int i = r / N_TOK, j = r % N_TOK;
    int di = i / 49, hi = (i % 49) / 7, wi = i % 7;
    int dj = j / 49, hj = (j % 49) / 7, wj = j % 7;
    int rel = (di - dj + 7) * 169 + (hi - hj + 6) * 13 + (wi - wj + 6);
    out[idx] = tab[rel * 4 + h];
}

// ---------------------------------------------------------------------------
// LN1 + cyclic shift (roll -4,-3,-3) + window partition -> bf16 (T_TOT,128)
// ---------------------------------------------------------------------------
__global__ __launch_bounds__(256) void ln1_part_k(
    const float* __restrict__ x, const float* __restrict__ w,
    const float* __restrict__ b, unsigned short* __restrict__ xw)
{
    const int t = blockIdx.x * 4 + (threadIdx.x >> 6);
    const int lane = threadIdx.x & 63;
    const int win = t / N_TOK, n = t % N_TOK;
    const int wd = win >> 6, wh = (win >> 3) & 7, ww = win & 7;
    const int td = n / 49, rr = n % 49, th = rr / 7, tw = rr % 7;
    const int gd = wd * 8 + td, gh = wh * 7 + th, gw = ww * 7 + tw;
    const int sd = (gd + 4) & 15;
    int sh = gh + 3; if (sh >= 56) sh -= 56;
    int sw = gw + 3; if (sw >= 56) sw -= 56;
    const float* px = x + (((size_t)sd * 56 + sh) * 56 + sw) * 128;
    float v0 = px[lane], v1 = px[lane + 64];
    float s = v0 + v1, s2 = v0 * v0 + v1 * v1;
#pragma unroll
    for (int o = 32; o > 0; o >>= 1) { s += __shfl_xor(s, o); s2 += __shfl_xor(s2, o); }
    float mu = s * (1.f / 128.f);
    float var = s2 * (1.f / 128.f) - mu * mu;
    float rstd = rsqrtf(var + 1e-5f);
    unsigned short* po = xw + (size_t)t * 128;
    po[lane]      = f2bf((v0 - mu) * rstd * w[lane]      + b[lane]);
    po[lane + 64] = f2bf((v1 - mu) * rstd * w[lane + 64] + b[lane + 64]);
}

// ---------------------------------------------------------------------------
// LN2 (image token order) -> bf16
// ---------------------------------------------------------------------------
__global__ __launch_bounds__(256) void ln2_k(
    const float* __restrict__ x1, const float* __restrict__ w,
    const float* __restrict__ b, unsigned short* __restrict__ xn)
{
    const int t = blockIdx.x * 4 + (threadIdx.x >> 6);
    const int lane = threadIdx.x & 63;
    const float* px = x1 + (size_t)t * 128;
    float v0 = px[lane], v1 = px[lane + 64];
    float s = v0 + v1, s2 = v0 * v0 + v1 * v1;
#pragma unroll
    for (int o = 32; o > 0; o >>= 1) { s += __shfl_xor(s, o); s2 += __shfl_xor(s2, o); }
    float mu = s * (1.f / 128.f);
    float var = s2 * (1.f / 128.f) - mu * mu;
    float rstd = rsqrtf(var + 1e-5f);
    unsigned short* po = xn + (size_t)t * 128;
    po[lane]      = f2bf((v0 - mu) * rstd * w[lane]      + b[lane]);
    po[lane + 64] = f2bf((v1 - mu) * rstd * w[lane + 64] + b[lane + 64]);
}

// ---------------------------------------------------------------------------
// bf16 MFMA GEMM, 128x128 tile, 4 waves (2x2), 64x64 per wave, BK=64.
// ---------------------------------------------------------------------------
template<int K, int EPI>
__global__ __launch_bounds__(256, 2) void gemm_k(
    const unsigned short* __restrict__ A,
    const unsigned short* __restrict__ Bt,
    const float* __restrict__ bias,
    const float* __restrict__ resid,
    void* __restrict__ outp)
{
    __shared__ __align__(16) unsigned short Asl[128 * 64];
    __shared__ __align__(16) unsigned short Bsl[128 * 64];
    const int bm = blockIdx.x * 128;
    const int bn = blockIdx.y * 128;
    const int tid = threadIdx.x;
    const int lane = tid & 63;
    const int wave = tid >> 6;
    const int wr = wave >> 1, wc = wave & 1;
    const int lr = lane & 15;
    const int lk = (lane >> 4) << 3;

    fp32x4 acc[4][4];
#pragma unroll
    for (int i = 0; i < 4; ++i)
#pragma unroll
        for (int j = 0; j < 4; ++j) acc[i][j] = {0.f, 0.f, 0.f, 0.f};

    for (int ks = 0; ks < K; ks += 64) {
        __syncthreads();
#pragma unroll
        for (int it = 0; it < 4; ++it) {
            int chunk = it * 256 + tid;
            int row = chunk >> 3;
            int kc = (chunk & 7) << 3;
            *(uint4*)&Asl[row * 64 + kc] =
                *(const uint4*)&A[(size_t)(bm + row) * K + ks + kc];
            *(uint4*)&Bsl[row * 64 + kc] =
                *(const uint4*)&Bt[(size_t)(bn + row) * K + ks + kc];
        }
        __syncthreads();
#pragma unroll
        for (int kk = 0; kk < 64; kk += 32) {
            s16x8 af[4], bfr[4];
#pragma unroll
            for (int mb = 0; mb < 4; ++mb)
                af[mb] = *(const s16x8*)&Asl[(wr * 64 + mb * 16 + lr) * 64 + kk + lk];
#pragma unroll
            for (int nb = 0; nb < 4; ++nb)
                bfr[nb] = *(const s16x8*)&Bsl[(wc * 64 + nb * 16 + lr) * 64 + kk + lk];
#pragma unroll
            for (int mb = 0; mb < 4; ++mb)
#pragma unroll
                for (int nb = 0; nb < 4; ++nb)
                    acc[mb][nb] = __builtin_amdgcn_mfma_f32_16x16x32_bf16(
                        af[mb], bfr[nb], acc[mb][nb], 0, 0, 0);
        }
    }

    const int crow = (lane >> 4) << 2;
    const int ccol = lane & 15;
#pragma unroll
    for (int mb = 0; mb < 4; ++mb) {
#pragma unroll
        for (int nb = 0; nb < 4; ++nb) {
#pragma unroll
            for (int r = 0; r < 4; ++r) {
                const int grow = bm + wr * 64 + mb * 16 + crow + r;
                const int gcol = bn + wc * 64 + nb * 16 + ccol;
                float v = acc[mb][nb][r] + bias[gcol];
                if (EPI == 0) {
                    if (gcol < 128) v *= 0.17677669529663687f;   // HEAD^-0.5
                    ((unsigned short*)outp)[(size_t)grow * 384 + gcol] = f2bf(v);
                } else if (EPI == 1) {
                    int w  = grow / N_TOK, n = grow % N_TOK;
                    int wd = w >> 6, wh = (w >> 3) & 7, ww = w & 7;
                    int td = n / 49, rr = n % 49, th = rr / 7, tw = rr % 7;
                    int gd = wd * 8 + td, gh = wh * 7 + th, gw = ww * 7 + tw;
                    int sd = (gd + 4) & 15;
                    int sh = gh + 3; if (sh >= 56) sh -= 56;
                    int sw = gw + 3; if (sw >= 56) sw -= 56;
                    size_t oi = (((size_t)sd * 56 + sh) * 56 + sw) * 128 + gcol;
                    ((float*)outp)[oi] = v + resid[oi];
                } else if (EPI == 2) {
                    v = 0.5f * v * (1.f + erff(v * 0.70710678118654752f));
                    ((unsigned short*)outp)[(size_t)grow * 512 + gcol] = f2bf(v);
                } else {
                    size_t oi = (size_t)grow * 128 + gcol;
                    ((float*)outp)[oi] = v + resid[oi];
                }
            }
        }
    }
}

// ---------------------------------------------------------------------------
// MFMA attention: one block per (window, head) = 512 blocks, 4 waves.
// Tokens padded 392 -> 416 (26 tiles of 16; 13 k-steps of 32 for PV).
// K staged [416][40] bf16; V staged transposed [32][424]; P per-wave [16][424].
// Softmax wave-parallel in-register (C-layout groups + shfl_xor).
// ---------------------------------------------------------------------------
#define KSTR 40
#define VSTR 424
#define PSTR 424

__global__ __launch_bounds__(256, 1) void attn_k(
    const unsigned short* __restrict__ qkv,
    const float* __restrict__ btab,
    unsigned short* __restrict__ y)
{
    __shared__ __align__(16) unsigned short Ksh[416 * KSTR];
    __shared__ __align__(16) unsigned short Vt[32 * VSTR];
    __shared__ __align__(16) unsigned short Psh[4][16 * PSTR];
    __shared__ unsigned char rid_sh[416];

    const int blk = blockIdx.x;
    const int wI = blk >> 2, h = blk & 3;
    const int tid = threadIdx.x;
    const int wave = tid >> 6, lane = tid & 63;
    const int lr = lane & 15, g = lane >> 4, lk = g << 3;
    const unsigned short* base = qkv + (size_t)wI * N_TOK * 384;

    const int wd = wI >> 6, wh = (wI >> 3) & 7, ww = wI & 7;
    const bool boundary = (wd == 1) | (wh == 7) | (ww == 7);

    // ---- stage K natural [token][chan] ----
    for (int idx = tid; idx < 392 * 4; idx += 256) {
        int j = idx >> 2, c0 = (idx & 3) << 3;
        *(uint4*)&Ksh[j * KSTR + c0] =
            *(const uint4*)&base[(size_t)j * 384 + 128 + h * 32 + c0];
    }
    for (int idx = tid; idx < 24 * 4; idx += 256) {       // zero pad rows
        int j = 392 + (idx >> 2), c0 = (idx & 3) << 3;
        u16x8 z = {};
        *(u16x8*)&Ksh[j * KSTR + c0] = z;
    }
    // ---- stage V transposed [chan][token] ----
    for (int idx = tid; idx < 32 * 49; idx += 256) {
        int c = idx & 31, j0 = (idx >> 5) << 3;
        const unsigned short* vp = base + 256 + h * 32 + c;
        u16x8 tmp;
#pragma unroll
        for (int i = 0; i < 8; ++i) tmp[i] = vp[(size_t)(j0 + i) * 384];
        *(u16x8*)&Vt[c * VSTR + j0] = tmp;
    }
    for (int idx = tid; idx < 32 * 3; idx += 256) {       // zero pad cols
        int c = idx & 31, j0 = 392 + ((idx >> 5) << 3);
        u16x8 z = {};
        *(u16x8*)&Vt[c * VSTR + j0] = z;
    }
    // ---- region ids for the shift mask ----
    for (int n = tid; n < 416; n += 256) {
        int nn = (n < 392) ? n : 391;
        int td = nn / 49, rr = nn % 49, th = rr / 7, tw = rr % 7;
        int gd = wd * 8 + td, gh = wh * 7 + th, gw = ww * 7 + tw;
        int r = ((gd < 8) ? 0 : ((gd < 12) ? 9 : 18)) +
                ((gh < 49) ? 0 : ((gh < 53) ? 3 : 6)) +
                ((gw < 49) ? 0 : ((gw < 53) ? 1 : 2));
        rid_sh[n] = (unsigned char)r;
    }
    __syncthreads();

    const float* bb = btab + (size_t)h * N_TOK * N_TOK;
    unsigned short* pw = &Psh[wave][0];

    for (int rt = wave; rt < 25; rt += 4) {
        // ---- QK^T: 26 MFMAs ----
        const int qrow = (rt * 16 + lr < 392) ? rt * 16 + lr : 391;
        s16x8 aq = *(const s16x8*)&base[(size_t)qrow * 384 + h * 32 + lk];
        fp32x4 acc[26];
#pragma unroll
        for (int ct = 0; ct < 26; ++ct) {
            s16x8 bk = *(const s16x8*)&Ksh[(ct * 16 + lr) * KSTR + lk];
            fp32x4 z = {0.f, 0.f, 0.f, 0.f};
            acc[ct] = __builtin_amdgcn_mfma_f32_16x16x32_bf16(aq, bk, z, 0, 0, 0);
        }
        // ---- bias + mask + row max ----
        const int i0 = rt * 16 + (g << 2);
        unsigned char ri[4];
        int ic[4];
#pragma unroll
        for (int r = 0; r < 4; ++r) {
            ic[r] = (i0 + r < 392) ? i0 + r : 391;
            ri[r] = rid_sh[ic[r]];
        }
        float mx[4] = {-1e30f, -1e30f, -1e30f, -1e30f};
#pragma unroll
        for (int ct = 0; ct < 26; ++ct) {
            int j = ct * 16 + lr;
            bool jv = j < 392;
            int jc = jv ? j : 391;
            unsigned char rj = rid_sh[jc];
#pragma unroll
            for (int r = 0; r < 4; ++r) {
                float s = acc[ct][r] + bb[(size_t)ic[r] * N_TOK + jc];
                if (boundary && (ri[r] != rj)) s -= 100.f;
                if (!jv) s = -1e30f;
                acc[ct][r] = s;
                mx[r] = fmaxf(mx[r], s);
            }
        }
#pragma unroll
        for (int r = 0; r < 4; ++r)
#pragma unroll
            for (int m = 1; m < 16; m <<= 1)
                mx[r] = fmaxf(mx[r], __shfl_xor(mx[r], m));
        // ---- exp + row sum ----
        float sum[4] = {0.f, 0.f, 0.f, 0.f};
#pragma unroll
        for (int ct = 0; ct < 26; ++ct)
#pragma unroll
            for (int r = 0; r < 4; ++r) {
                float p = __expf(acc[ct][r] - mx[r]);
                acc[ct][r] = p;
                sum[r] += p;
            }
#pragma unroll
        for (int r = 0; r < 4; ++r) {
#pragma unroll
            for (int m = 1; m < 16; m <<= 1) sum[r] += __shfl_xor(sum[r], m);
            sum[r] = 1.f / sum[r];
        }
        // ---- write P (bf16, normalized) ----
#pragma unroll
        for (int ct = 0; ct < 26; ++ct)
#pragma unroll
            for (int r = 0; r < 4; ++r)
                pw[((g << 2) + r) * PSTR + ct * 16 + lr] = f2bf(acc[ct][r] * sum[r]);
        // ---- PV: 13 k-steps x 2 col tiles ----
        fp32x4 o0 = {0.f, 0.f, 0.f, 0.f}, o1 = {0.f, 0.f, 0.f, 0.f};
#pragma unroll
        for (int ks = 0; ks < 13; ++ks) {
            s16x8 ap  = *(const s16x8*)&pw[lr * PSTR + ks * 32 + lk];
            s16x8 bv0 = *(const s16x8*)&Vt[lr * VSTR + ks * 32 + lk];
            s16x8 bv1 = *(const s16x8*)&Vt[(16 + lr) * VSTR + ks * 32 + lk];
            o0 = __builtin_amdgcn_mfma_f32_16x16x32_bf16(ap, bv0, o0, 0, 0, 0);
            o1 = __builtin_amdgcn_mfma_f32_16x16x32_bf16(ap, bv1, o1, 0, 0, 0);
        }
        // ---- write O ----
#pragma unroll
        for (int r = 0; r < 4; ++r) {
            int row = rt * 16 + (g << 2) + r;
            if (row < 392) {
                size_t ob = ((size_t)wI * N_TOK + row) * 128 + h * 32;
                y[ob + lr]      = f2bf(o0[r]);
                y[ob + 16 + lr] = f2bf(o1[r]);
            }
        }
    }
}

// ---------------------------------------------------------------------------
extern "C" void kernel_launch(void* const* d_in, const int* in_sizes, int n_in,
                              void* d_out, int out_size, void* d_ws, size_t ws_size,
                              hipStream_t stream)
{
    const float* x      = (const float*)d_in[0];
    const float* n1w    = (const float*)d_in[1];
    const float* n1b    = (const float*)d_in[2];
    const float* qkv_w  = (const float*)d_in[3];
    const float* qkv_b  = (const float*)d_in[4];
    const float* rpt    = (const float*)d_in[5];
    const float* proj_w = (const float*)d_in[6];
    const float* proj_b = (const float*)d_in[7];
    const float* n2w    = (const float*)d_in[8];
    const float* n2b    = (const float*)d_in[9];
    const float* fc1_w  = (const float*)d_in[10];
    const float* fc1_b  = (const float*)d_in[11];
    const float* fc2_w  = (const float*)d_in[12];
    const float* fc2_b  = (const float*)d_in[13];

    char* ws = (char*)d_ws;
    unsigned short* xw  = (unsigned short*)(ws);                  // T*128 bf16
    unsigned short* qkv = (unsigned short*)(ws + 12845056);       // T*384 bf16
    unsigned short* y   = (unsigned short*)(ws + 51380224);       // T*128 bf16
    float*          x1  = (float*)         (ws + 64225280);       // T*128 f32
    unsigned short* xn  = (unsigned short*)(ws + 89915392);       // T*128 bf16
    unsigned short* hid = (unsigned short*)(ws + 102760448);      // T*512 bf16
    unsigned short* wq  = (unsigned short*)(ws + 154140672);      // 384*128 bf16
    unsigned short* wp  = (unsigned short*)(ws + 154238976);      // 128*128 bf16
    unsigned short* w1  = (unsigned short*)(ws + 154271744);      // 512*128 bf16
    unsigned short* w2  = (unsigned short*)(ws + 154402816);      // 128*512 bf16
    float*          bt  = (float*)         (ws + 154533888);      // 4*392*392 f32

    hipLaunchKernelGGL(cvt_w_k, dim3(256), dim3(256), 0, stream,
                       qkv_w, proj_w, fc1_w, fc2_w, wq, wp, w1, w2);
    hipLaunchKernelGGL(bias_tab_k, dim3((4 * N_TOK * N_TOK + 255) / 256), dim3(256),
                       0, stream, rpt, bt);
    hipLaunchKernelGGL(ln1_part_k, dim3(T_TOT / 4), dim3(256), 0, stream,
                       x, n1w, n1b, xw);
    hipLaunchKernelGGL((gemm_k<128, 0>), dim3(392, 3), dim3(256), 0, stream,
                       xw, wq, qkv_b, (const float*)nullptr, (void*)qkv);
    hipLaunchKernelGGL(attn_k, dim3(512), dim3(256), 0, stream, qkv, bt, y);
    hipLaunchKernelGGL((gemm_k<128, 1>), dim3(392, 1), dim3(256), 0, stream,
                       y, wp, proj_b, x, (void*)x1);
    hipLaunchKernelGGL(ln2_k, dim3(T_TOT / 4), dim3(256), 0, stream,
                       x1, n2w, n2b, xn);
    hipLaunchKernelGGL((gemm_k<128, 2>), dim3(392, 4), dim3(256), 0, stream,
                       xn, w1, fc1_b, (const float*)nullptr, (void*)hid);
    hipLaunchKernelGGL((gemm_k<512, 3>), dim3(392, 1), dim3(256), 0, stream,
                       hid, w2, fc2_b, x1, d_out);
}

// Round 5
// 257.181 us; speedup vs baseline: 4.0338x; 1.1779x over previous
//
#include <hip/hip_runtime.h>
#include <hip/hip_bf16.h>
#include <math.h>

// ---------------------------------------------------------------------------
// Swin Transformer 3D block, MI355X (gfx950)
// B=1, D=16, H=56, W=56, C=128, NH=4, HEAD=32, window 8x7x7 (N=392), shift 4,3,3
// Round 5: attn_k rework — swapped QK^T (row lane-local softmax), float4 bias,
// tiny per-wave LDS transpose for P (no 54KB Psh), LDS 115->66KB => 2 blk/CU.
// ---------------------------------------------------------------------------

typedef short s16x8 __attribute__((ext_vector_type(8)));
typedef unsigned short u16x8 __attribute__((ext_vector_type(8)));
typedef float fp32x4 __attribute__((ext_vector_type(4)));

#define T_TOT 50176      // total tokens = 128 windows * 392
#define N_TOK 392
#define N_WIN 128

__device__ __forceinline__ unsigned short f2bf(float f) {
    union { float f; unsigned u; } v; v.f = f;
    unsigned r = v.u + 0x7FFFu + ((v.u >> 16) & 1u);   // RNE
    return (unsigned short)(r >> 16);
}
__device__ __forceinline__ float bf2f(unsigned short u) {
    union { unsigned u; float f; } v; v.u = ((unsigned)u) << 16;
    return v.f;
}

// ---------------------------------------------------------------------------
// Weight fp32 -> bf16 conversion (one small kernel, all four weights)
// ---------------------------------------------------------------------------
__global__ void cvt_w_k(const float* __restrict__ wq, const float* __restrict__ wp,
                        const float* __restrict__ w1, const float* __restrict__ w2,
                        unsigned short* __restrict__ oq, unsigned short* __restrict__ op,
                        unsigned short* __restrict__ o1, unsigned short* __restrict__ o2)
{
    int i = blockIdx.x * 256 + threadIdx.x;
    if (i < 384 * 128) oq[i] = f2bf(wq[i]);
    if (i < 128 * 128) op[i] = f2bf(wp[i]);
    if (i < 512 * 128) { o1[i] = f2bf(w1[i]); o2[i] = f2bf(w2[i]); }
}

// ---------------------------------------------------------------------------
// Relative-position bias table: bias[h][i][j] = rel_pos_table[rel_idx(i,j)][h]
// ---------------------------------------------------------------------------
__global__ void bias_tab_k(const float* __restrict__ tab, float* __restrict__ out)
{
    int idx = blockIdx.x * 256 + threadIdx.x;
    if (idx >= 4 * N_TOK * N_TOK) return;
    int h = idx / (N_TOK * N_TOK), r = idx % (N_TOK * N_TOK);
    int i = r / N_TOK, j = r % N_TOK;
    int di = i / 49, hi = (i % 49) / 7, wi = i % 7;
    int dj = j / 49, hj = (j % 49) / 7, wj = j % 7;
    int rel = (di - dj + 7) * 169 + (hi - hj + 6) * 13 + (wi - wj + 6);
    out[idx] = tab[rel * 4 + h];
}

// ---------------------------------------------------------------------------
// LN1 + cyclic shift (roll -4,-3,-3) + window partition -> bf16 (T_TOT,128)
// ---------------------------------------------------------------------------
__global__ __launch_bounds__(256) void ln1_part_k(
    const float* __restrict__ x, const float* __restrict__ w,
    const float* __restrict__ b, unsigned short* __restrict__ xw)
{
    const int t = blockIdx.x * 4 + (threadIdx.x >> 6);
    const int lane = threadIdx.x & 63;
    const int win = t / N_TOK, n = t % N_TOK;
    const int wd = win >> 6, wh = (win >> 3) & 7, ww = win & 7;
    const int td = n / 49, rr = n % 49, th = rr / 7, tw = rr % 7;
    const int gd = wd * 8 + td, gh = wh * 7 + th, gw = ww * 7 + tw;
    const int sd = (gd + 4) & 15;
    int sh = gh + 3; if (sh >= 56) sh -= 56;
    int sw = gw + 3; if (sw >= 56) sw -= 56;
    const float* px = x + (((size_t)sd * 56 + sh) * 56 + sw) * 128;
    float v0 = px[lane], v1 = px[lane + 64];
    float s = v0 + v1, s2 = v0 * v0 + v1 * v1;
#pragma unroll
    for (int o = 32; o > 0; o >>= 1) { s += __shfl_xor(s, o); s2 += __shfl_xor(s2, o); }
    float mu = s * (1.f / 128.f);
    float var = s2 * (1.f / 128.f) - mu * mu;
    float rstd = rsqrtf(var + 1e-5f);
    unsigned short* po = xw + (size_t)t * 128;
    po[lane]      = f2bf((v0 - mu) * rstd * w[lane]      + b[lane]);
    po[lane + 64] = f2bf((v1 - mu) * rstd * w[lane + 64] + b[lane + 64]);
}

// ---------------------------------------------------------------------------
// LN2 (image token order) -> bf16
// ---------------------------------------------------------------------------
__global__ __launch_bounds__(256) void ln2_k(
    const float* __restrict__ x1, const float* __restrict__ w,
    const float* __restrict__ b, unsigned short* __restrict__ xn)
{
    const int t = blockIdx.x * 4 + (threadIdx.x >> 6);
    const int lane = threadIdx.x & 63;
    const float* px = x1 + (size_t)t * 128;
    float v0 = px[lane], v1 = px[lane + 64];
    float s = v0 + v1, s2 = v0 * v0 + v1 * v1;
#pragma unroll
    for (int o = 32; o > 0; o >>= 1) { s += __shfl_xor(s, o); s2 += __shfl_xor(s2, o); }
    float mu = s * (1.f / 128.f);
    float var = s2 * (1.f / 128.f) - mu * mu;
    float rstd = rsqrtf(var + 1e-5f);
    unsigned short* po = xn + (size_t)t * 128;
    po[lane]      = f2bf((v0 - mu) * rstd * w[lane]      + b[lane]);
    po[lane + 64] = f2bf((v1 - mu) * rstd * w[lane + 64] + b[lane + 64]);
}

// ---------------------------------------------------------------------------
// bf16 MFMA GEMM, 128x128 tile, 4 waves (2x2), 64x64 per wave, BK=64.
// ---------------------------------------------------------------------------
template<int K, int EPI>
__global__ __launch_bounds__(256, 2) void gemm_k(
    const unsigned short* __restrict__ A,
    const unsigned short* __restrict__ Bt,
    const float* __restrict__ bias,
    const float* __restrict__ resid,
    void* __restrict__ outp)
{
    __shared__ __align__(16) unsigned short Asl[128 * 64];
    __shared__ __align__(16) unsigned short Bsl[128 * 64];
    const int bm = blockIdx.x * 128;
    const int bn = blockIdx.y * 128;
    const int tid = threadIdx.x;
    const int lane = tid & 63;
    const int wave = tid >> 6;
    const int wr = wave >> 1, wc = wave & 1;
    const int lr = lane & 15;
    const int lk = (lane >> 4) << 3;

    fp32x4 acc[4][4];
#pragma unroll
    for (int i = 0; i < 4; ++i)
#pragma unroll
        for (int j = 0; j < 4; ++j) acc[i][j] = {0.f, 0.f, 0.f, 0.f};

    for (int ks = 0; ks < K; ks += 64) {
        __syncthreads();
#pragma unroll
        for (int it = 0; it < 4; ++it) {
            int chunk = it * 256 + tid;
            int row = chunk >> 3;
            int kc = (chunk & 7) << 3;
            *(uint4*)&Asl[row * 64 + kc] =
                *(const uint4*)&A[(size_t)(bm + row) * K + ks + kc];
            *(uint4*)&Bsl[row * 64 + kc] =
                *(const uint4*)&Bt[(size_t)(bn + row) * K + ks + kc];
        }
        __syncthreads();
#pragma unroll
        for (int kk = 0; kk < 64; kk += 32) {
            s16x8 af[4], bfr[4];
#pragma unroll
            for (int mb = 0; mb < 4; ++mb)
                af[mb] = *(const s16x8*)&Asl[(wr * 64 + mb * 16 + lr) * 64 + kk + lk];
#pragma unroll
            for (int nb = 0; nb < 4; ++nb)
                bfr[nb] = *(const s16x8*)&Bsl[(wc * 64 + nb * 16 + lr) * 64 + kk + lk];
#pragma unroll
            for (int mb = 0; mb < 4; ++mb)
#pragma unroll
                for (int nb = 0; nb < 4; ++nb)
                    acc[mb][nb] = __builtin_amdgcn_mfma_f32_16x16x32_bf16(
                        af[mb], bfr[nb], acc[mb][nb], 0, 0, 0);
        }
    }

    const int crow = (lane >> 4) << 2;
    const int ccol = lane & 15;
#pragma unroll
    for (int mb = 0; mb < 4; ++mb) {
#pragma unroll
        for (int nb = 0; nb < 4; ++nb) {
#pragma unroll
            for (int r = 0; r < 4; ++r) {
                const int grow = bm + wr * 64 + mb * 16 + crow + r;
                const int gcol = bn + wc * 64 + nb * 16 + ccol;
                float v = acc[mb][nb][r] + bias[gcol];
                if (EPI == 0) {
                    if (gcol < 128) v *= 0.17677669529663687f;   // HEAD^-0.5
                    ((unsigned short*)outp)[(size_t)grow * 384 + gcol] = f2bf(v);
                } else if (EPI == 1) {
                    int w  = grow / N_TOK, n = grow % N_TOK;
                    int wd = w >> 6, wh = (w >> 3) & 7, ww = w & 7;
                    int td = n / 49, rr = n % 49, th = rr / 7, tw = rr % 7;
                    int gd = wd * 8 + td, gh = wh * 7 + th, gw = ww * 7 + tw;
                    int sd = (gd + 4) & 15;
                    int sh = gh + 3; if (sh >= 56) sh -= 56;
                    int sw = gw + 3; if (sw >= 56) sw -= 56;
                    size_t oi = (((size_t)sd * 56 + sh) * 56 + sw) * 128 + gcol;
                    ((float*)outp)[oi] = v + resid[oi];
                } else if (EPI == 2) {
                    v = 0.5f * v * (1.f + erff(v * 0.70710678118654752f));
                    ((unsigned short*)outp)[(size_t)grow * 512 + gcol] = f2bf(v);
                } else {
                    size_t oi = (size_t)grow * 128 + gcol;
                    ((float*)outp)[oi] = v + resid[oi];
                }
            }
        }
    }
}

// ---------------------------------------------------------------------------
// MFMA attention v2: one block per (window, head) = 512 blocks, 4 waves.
// Swapped QK^T: acc[ct] = mfma(K_rows, Q_rows) -> lane (g,lr) holds
// S[i = rt*16+lr][j = ct*16+g*4+r]  (query row lane-local => cheap softmax).
// ct ranges 0..24 (j < 400); j >= 392 handled as g>=2 invalid at ct=24.
// P transposed to MFMA-A layout via per-wave 16x40 LDS tile (barrier-free).
// LDS ~66KB => 2 blocks/CU (8 waves/CU), all 512 blocks resident.
// ---------------------------------------------------------------------------
#define KSTR 40
#define VSTR 424
#define PTS  40          // per-wave P transpose tile stride (u16)

__global__ __launch_bounds__(256, 2) void attn_k(
    const unsigned short* __restrict__ qkv,
    const float* __restrict__ btab,
    unsigned short* __restrict__ y)
{
    __shared__ __align__(16) unsigned short Ksh[416 * KSTR];
    __shared__ __align__(16) unsigned short Vt[32 * VSTR];
    __shared__ __align__(16) unsigned short Pt[4][16 * PTS];
    __shared__ __align__(4) unsigned char rid_sh[416];

    const int blk = blockIdx.x;
    const int wI = blk >> 2, h = blk & 3;
    const int tid = threadIdx.x;
    const int wave = tid >> 6, lane = tid & 63;
    const int lr = lane & 15, g = lane >> 4, lk = g << 3;
    const unsigned short* base = qkv + (size_t)wI * N_TOK * 384;

    const int wd = wI >> 6, wh = (wI >> 3) & 7, ww = wI & 7;
    const bool boundary = (wd == 1) | (wh == 7) | (ww == 7);

    // ---- stage K natural [token][chan] ----
    for (int idx = tid; idx < 392 * 4; idx += 256) {
        int j = idx >> 2, c0 = (idx & 3) << 3;
        *(uint4*)&Ksh[j * KSTR + c0] =
            *(const uint4*)&base[(size_t)j * 384 + 128 + h * 32 + c0];
    }
    for (int idx = tid; idx < 24 * 4; idx += 256) {       // zero pad rows
        int j = 392 + (idx >> 2), c0 = (idx & 3) << 3;
        u16x8 z = {};
        *(u16x8*)&Ksh[j * KSTR + c0] = z;
    }
    // ---- stage V transposed [chan][token] ----
    for (int idx = tid; idx < 32 * 49; idx += 256) {
        int c = idx & 31, j0 = (idx >> 5) << 3;
        const unsigned short* vp = base + 256 + h * 32 + c;
        u16x8 tmp;
#pragma unroll
        for (int i = 0; i < 8; ++i) tmp[i] = vp[(size_t)(j0 + i) * 384];
        *(u16x8*)&Vt[c * VSTR + j0] = tmp;
    }
    for (int idx = tid; idx < 32 * 3; idx += 256) {       // zero pad cols
        int c = idx & 31, j0 = 392 + ((idx >> 5) << 3);
        u16x8 z = {};
        *(u16x8*)&Vt[c * VSTR + j0] = z;
    }
    // ---- region ids for the shift mask ----
    for (int n = tid; n < 416; n += 256) {
        int nn = (n < 392) ? n : 391;
        int td = nn / 49, rr = nn % 49, th = rr / 7, tw = rr % 7;
        int gd = wd * 8 + td, gh = wh * 7 + th, gw = ww * 7 + tw;
        int r = ((gd < 8) ? 0 : ((gd < 12) ? 9 : 18)) +
                ((gh < 49) ? 0 : ((gh < 53) ? 3 : 6)) +
                ((gw < 49) ? 0 : ((gw < 53) ? 1 : 2));
        rid_sh[n] = (unsigned char)r;
    }
    __syncthreads();

    const float* bb = btab + (size_t)h * N_TOK * N_TOK;
    unsigned short* pw = &Pt[wave][0];
    const int j0 = g << 2;

    for (int rt = wave; rt < 25; rt += 4) {
        // ---- swapped QK^T: 25 MFMAs; C[j][i] ----
        const int irow = rt * 16 + lr;
        const int ic = (irow < 392) ? irow : 391;
        s16x8 bq = *(const s16x8*)&base[(size_t)ic * 384 + h * 32 + lk];
        fp32x4 acc[25];
#pragma unroll
        for (int ct = 0; ct < 25; ++ct) {
            s16x8 ak = *(const s16x8*)&Ksh[(ct * 16 + lr) * KSTR + lk];
            fp32x4 z = {0.f, 0.f, 0.f, 0.f};
            acc[ct] = __builtin_amdgcn_mfma_f32_16x16x32_bf16(ak, bq, z, 0, 0, 0);
        }
        // ---- bias (float4) + mask (packed rid) + row max (in-lane) ----
        const int ri = rid_sh[ic];
        float mx = -1e30f;
#pragma unroll
        for (int ct = 0; ct < 24; ++ct) {
            float4 bv = *(const float4*)&bb[(size_t)ic * N_TOK + ct * 16 + j0];
            unsigned rj4 = *(const unsigned*)&rid_sh[ct * 16 + j0];
            const float bs[4] = {bv.x, bv.y, bv.z, bv.w};
#pragma unroll
            for (int r = 0; r < 4; ++r) {
                float s = acc[ct][r] + bs[r];
                int rj = (rj4 >> (8 * r)) & 255;
                if (boundary && rj != ri) s -= 100.f;
                acc[ct][r] = s;
                mx = fmaxf(mx, s);
            }
        }
        {   // ct = 24: j = 384 + g*4 + r, valid only for g < 2
            float4 bv = {0.f, 0.f, 0.f, 0.f};
            unsigned rj4 = 0;
            if (g < 2) {
                bv = *(const float4*)&bb[(size_t)ic * N_TOK + 384 + j0];
                rj4 = *(const unsigned*)&rid_sh[384 + j0];
            }
            const float bs[4] = {bv.x, bv.y, bv.z, bv.w};
#pragma unroll
            for (int r = 0; r < 4; ++r) {
                float s = -1e30f;
                if (g < 2) {
                    s = acc[24][r] + bs[r];
                    int rj = (rj4 >> (8 * r)) & 255;
                    if (boundary && rj != ri) s -= 100.f;
                }
                acc[24][r] = s;
                mx = fmaxf(mx, s);
            }
        }
        mx = fmaxf(mx, __shfl_xor(mx, 16));
        mx = fmaxf(mx, __shfl_xor(mx, 32));
        // ---- exp + row sum (in-lane + 2 shfl) ----
        float sum = 0.f;
#pragma unroll
        for (int ct = 0; ct < 25; ++ct)
#pragma unroll
            for (int r = 0; r < 4; ++r) {
                float p = __expf(acc[ct][r] - mx);
                acc[ct][r] = p;
                sum += p;
            }
        sum += __shfl_xor(sum, 16);
        sum += __shfl_xor(sum, 32);
        const float rs = 1.f / sum;
        // ---- PV: per k-step, transpose P through per-wave LDS tile ----
        fp32x4 o0 = {0.f, 0.f, 0.f, 0.f}, o1 = {0.f, 0.f, 0.f, 0.f};
#pragma unroll
        for (int ks = 0; ks < 13; ++ks) {
            // pack unnormalized P (<=1) to bf16 pairs: j = ct*16 + g*4 + {0..3}
            unsigned w0, w1, w2 = 0, w3 = 0;
            asm("v_cvt_pk_bf16_f32 %0, %1, %2"
                : "=v"(w0) : "v"(acc[2 * ks][0]), "v"(acc[2 * ks][1]));
            asm("v_cvt_pk_bf16_f32 %0, %1, %2"
                : "=v"(w1) : "v"(acc[2 * ks][2]), "v"(acc[2 * ks][3]));
            if (ks < 12) {
                asm("v_cvt_pk_bf16_f32 %0, %1, %2"
                    : "=v"(w2) : "v"(acc[2 * ks + 1][0]), "v"(acc[2 * ks + 1][1]));
                asm("v_cvt_pk_bf16_f32 %0, %1, %2"
                    : "=v"(w3) : "v"(acc[2 * ks + 1][2]), "v"(acc[2 * ks + 1][3]));
            }
            // write C-layout, read A-layout (in-wave ordering, no barrier)
            *(unsigned*)&pw[lr * PTS + j0]          = w0;
            *(unsigned*)&pw[lr * PTS + j0 + 2]      = w1;
            *(unsigned*)&pw[lr * PTS + 16 + j0]     = w2;
            *(unsigned*)&pw[lr * PTS + 16 + j0 + 2] = w3;
            s16x8 ap  = *(const s16x8*)&pw[lr * PTS + lk];
            s16x8 bv0 = *(const s16x8*)&Vt[lr * VSTR + ks * 32 + lk];
            s16x8 bv1 = *(const s16x8*)&Vt[(16 + lr) * VSTR + ks * 32 + lk];
            o0 = __builtin_amdgcn_mfma_f32_16x16x32_bf16(ap, bv0, o0, 0, 0, 0);
            o1 = __builtin_amdgcn_mfma_f32_16x16x32_bf16(ap, bv1, o1, 0, 0, 0);
        }
        // ---- write O (normalize by row sums fetched via shfl) ----
#pragma unroll
        for (int r = 0; r < 4; ++r) {
            const float rsr = __shfl(rs, (g << 2) + r);
            const int row = rt * 16 + (g << 2) + r;
            if (row < 392) {
                size_t ob = ((size_t)wI * N_TOK + row) * 128 + h * 32;
                y[ob + lr]      = f2bf(o0[r] * rsr);
                y[ob + 16 + lr] = f2bf(o1[r] * rsr);
            }
        }
    }
}

// ---------------------------------------------------------------------------
extern "C" void kernel_launch(void* const* d_in, const int* in_sizes, int n_in,
                              void* d_out, int out_size, void* d_ws, size_t ws_size,
                              hipStream_t stream)
{
    const float* x      = (const float*)d_in[0];
    const float* n1w    = (const float*)d_in[1];
    const float* n1b    = (const float*)d_in[2];
    const float* qkv_w  = (const float*)d_in[3];
    const float* qkv_b  = (const float*)d_in[4];
    const float* rpt    = (const float*)d_in[5];
    const float* proj_w = (const float*)d_in[6];
    const float* proj_b = (const float*)d_in[7];
    const float* n2w    = (const float*)d_in[8];
    const float* n2b    = (const float*)d_in[9];
    const float* fc1_w  = (const float*)d_in[10];
    const float* fc1_b  = (const float*)d_in[11];
    const float* fc2_w  = (const float*)d_in[12];
    const float* fc2_b  = (const float*)d_in[13];

    char* ws = (char*)d_ws;
    unsigned short* xw  = (unsigned short*)(ws);                  // T*128 bf16
    unsigned short* qkv = (unsigned short*)(ws + 12845056);       // T*384 bf16
    unsigned short* y   = (unsigned short*)(ws + 51380224);       // T*128 bf16
    float*          x1  = (float*)         (ws + 64225280);       // T*128 f32
    unsigned short* xn  = (unsigned short*)(ws + 89915392);       // T*128 bf16
    unsigned short* hid = (unsigned short*)(ws + 102760448);      // T*512 bf16
    unsigned short* wq  = (unsigned short*)(ws + 154140672);      // 384*128 bf16
    unsigned short* wp  = (unsigned short*)(ws + 154238976);      // 128*128 bf16
    unsigned short* w1  = (unsigned short*)(ws + 154271744);      // 512*128 bf16
    unsigned short* w2  = (unsigned short*)(ws + 154402816);      // 128*512 bf16
    float*          bt  = (float*)         (ws + 154533888);      // 4*392*392 f32

    hipLaunchKernelGGL(cvt_w_k, dim3(256), dim3(256), 0, stream,
                       qkv_w, proj_w, fc1_w, fc2_w, wq, wp, w1, w2);
    hipLaunchKernelGGL(bias_tab_k, dim3((4 * N_TOK * N_TOK + 255) / 256), dim3(256),
                       0, stream, rpt, bt);
    hipLaunchKernelGGL(ln1_part_k, dim3(T_TOT / 4), dim3(256), 0, stream,
                       x, n1w, n1b, xw);
    hipLaunchKernelGGL((gemm_k<128, 0>), dim3(392, 3), dim3(256), 0, stream,
                       xw, wq, qkv_b, (const float*)nullptr, (void*)qkv);
    hipLaunchKernelGGL(attn_k, dim3(512), dim3(256), 0, stream, qkv, bt, y);
    hipLaunchKernelGGL((gemm_k<128, 1>), dim3(392, 1), dim3(256), 0, stream,
                       y, wp, proj_b, x, (void*)x1);
    hipLaunchKernelGGL(ln2_k, dim3(T_TOT / 4), dim3(256), 0, stream,
                       x1, n2w, n2b, xn);
    hipLaunchKernelGGL((gemm_k<128, 2>), dim3(392, 4), dim3(256), 0, stream,
                       xn, w1, fc1_b, (const float*)nullptr, (void*)hid);
    hipLaunchKernelGGL((gemm_k<512, 3>), dim3(392, 1), dim3(256), 0, stream,
                       hid, w2, fc2_b, x1, d_out);
}